// Round 8
// baseline (1351.992 us; speedup 1.0000x reference)
//
#include <hip/hip_runtime.h>

typedef float f32x4 __attribute__((ext_vector_type(4)));
typedef short s16x8 __attribute__((ext_vector_type(8)));
typedef short s16x4 __attribute__((ext_vector_type(4)));
typedef unsigned short ush;

constexpr int Bn = 4, Tn = 1024, Dn = 512, CAPn = 32768, Kn = 1024;
constexpr int ROWS = Bn * Tn; // 4096
constexpr float SCALE = 0.044194173824159216f; // 1/sqrt(512)
constexpr float MOM = 0.99f;
constexpr float RATE_B = 0.0025f; // 0.01 / B

// ---- workspace layout (byte offsets); ws proven >= 102.0e6 B ----
constexpr size_t OFF_NM    = 0;                      // bf16 [CAP][D]  (alias: mem_lo early)
constexpr size_t OFF_NMT   = 33554432;               // bf16 [D][CAP]  (alias: mem_hi early)
constexpr size_t OFF_OPART = 67108864;               // bf16 [4][ROWS][D] (late, 16.78M)
constexpr size_t OFF_ZP2   = 83886080;               // f32 [4][ROWS] (late)
// early union (dead before k_attnout writes opart/zp2):
constexpr size_t OFF_KHI   = 67108864;               // bf16 [ROWS][D]
constexpr size_t OFF_KLO   = 71303168;               // bf16 [ROWS][D]
constexpr size_t OFF_ZPART = 75497472;               // f32 [512][ROWS] (ends 83886080)
constexpr size_t OFF_PRIO  = 83951616;               // f32 [4][CAP]
constexpr size_t OFF_RANK  = 84475904;               // i32 [4][CAP]
constexpr size_t OFF_COMB  = 85000192;               // f32 [4] (+64: invl1)

#define MFMA(a, b, c) __builtin_amdgcn_mfma_f32_16x16x32_bf16((a), (b), (c), 0, 0, 0)

__device__ __forceinline__ ush bfrn(float x) {
  unsigned u = __float_as_uint(x);
  return (ush)((u + 0x7FFFu + ((u >> 16) & 1u)) >> 16);
}
__device__ __forceinline__ float bff(ush h) { return __uint_as_float(((unsigned)h) << 16); }

__device__ __forceinline__ void gl16(const ush* g, ush* l) {
  __builtin_amdgcn_global_load_lds(
      (const __attribute__((address_space(1))) void*)(uintptr_t)g,
      (__attribute__((address_space(3))) void*)(uintptr_t)l, 16, 0, 0);
}

// combined[b] = mean(importance[b,:,0])
__global__ void k_combined(const float* __restrict__ imp, float* __restrict__ comb) {
  __shared__ float red[256];
  int b = blockIdx.x;
  float s = 0.f;
  for (int t = threadIdx.x; t < Tn; t += 256) s += imp[(size_t)b * Tn + t];
  red[threadIdx.x] = s;
  __syncthreads();
  for (int off = 128; off > 0; off >>= 1) {
    if (threadIdx.x < (unsigned)off) red[threadIdx.x] += red[threadIdx.x + off];
    __syncthreads();
  }
  if (threadIdx.x == 0) comb[b] = red[0] * (1.0f / Tn);
}

// x -> hi (RTN bf16), lo (RTN bf16 of residual). 4 elems/thread.
__global__ void k_cvt_hilo(const float* __restrict__ x, ush* __restrict__ hi,
                           ush* __restrict__ lo) {
  size_t i = ((size_t)blockIdx.x * 256 + threadIdx.x) * 4;
  f32x4 v = *(const f32x4*)&x[i];
  s16x4 h, l;
#pragma unroll
  for (int j = 0; j < 4; ++j) {
    ush hh = bfrn(v[j]);
    h[j] = (short)hh;
    l[j] = (short)bfrn(v[j] - bff(hh));
  }
  *(s16x4*)&hi[i] = h;
  *(s16x4*)&lo[i] = l;
}

// Z partials: zpart[cb][t] = sum over this block's 64 c of exp(A[c,:].B[t,:])
__global__ __launch_bounds__(256, 2) void k_rowexp(const ush* __restrict__ Abf,
                                                   const ush* __restrict__ Bbf,
                                                   float* __restrict__ zpart) {
  __shared__ ush Bs[64 * 512];
  __shared__ float red[2][64];
  const int tid = threadIdx.x;
  const int lane = tid & 63, wid = tid >> 6;
  const int wc2 = wid >> 1, wt = wid & 1;
  const int l15 = lane & 15, g = lane >> 4;
  const int cb = blockIdx.x;
  const int cBase = cb * 64;

  s16x8 afr[2][16];
#pragma unroll
  for (int mi = 0; mi < 2; ++mi) {
    int c = cBase + wc2 * 32 + mi * 16 + l15;
#pragma unroll
    for (int ks = 0; ks < 16; ++ks)
      afr[mi][ks] = *(const s16x8*)&Abf[(size_t)c * Dn + ks * 32 + g * 8];
  }

  for (int tt = 0; tt < 64; ++tt) {
    const int tBase = tt * 64;
#pragma unroll
    for (int rr = 0; rr < 16; ++rr) {
      int idx = rr * 256 + tid;
      int row = idx >> 6, ch = idx & 63;
      gl16(&Bbf[(size_t)(tBase + row) * Dn + ((ch ^ (row & 7)) << 3)],
           &Bs[rr * 2048 + wid * 512]);
    }
    __syncthreads();
    f32x4 S[2][2];
#pragma unroll
    for (int mi = 0; mi < 2; ++mi)
#pragma unroll
      for (int ni = 0; ni < 2; ++ni) S[mi][ni] = (f32x4){0.f, 0.f, 0.f, 0.f};
#pragma unroll
    for (int ks = 0; ks < 16; ++ks) {
      s16x8 bfr[2];
#pragma unroll
      for (int ni = 0; ni < 2; ++ni) {
        int trow = wt * 32 + ni * 16 + l15;
        bfr[ni] = *(const s16x8*)&Bs[trow * 512 + (((ks * 4 + g) ^ (trow & 7)) * 8)];
      }
#pragma unroll
      for (int mi = 0; mi < 2; ++mi)
#pragma unroll
        for (int ni = 0; ni < 2; ++ni) S[mi][ni] = MFMA(afr[mi][ks], bfr[ni], S[mi][ni]);
    }
    float tacc[2] = {0.f, 0.f};
#pragma unroll
    for (int mi = 0; mi < 2; ++mi)
#pragma unroll
      for (int ni = 0; ni < 2; ++ni)
#pragma unroll
        for (int r = 0; r < 4; ++r) tacc[ni] += __expf(S[mi][ni][r]);
#pragma unroll
    for (int ni = 0; ni < 2; ++ni) {
      float v = tacc[ni];
      v += __shfl_xor(v, 16);
      v += __shfl_xor(v, 32);
      tacc[ni] = v;
    }
    if (g == 0) {
      red[wc2][wt * 32 + l15] = tacc[0];
      red[wc2][wt * 32 + 16 + l15] = tacc[1];
    }
    __syncthreads();
    if (tid < 64) zpart[(size_t)cb * ROWS + tBase + tid] = red[0][tid] + red[1][tid];
  }
}

__global__ void k_invl(const float* __restrict__ zpart, float* __restrict__ invl) {
  int t = blockIdx.x * 256 + threadIdx.x;
  float s = 0.f;
  for (int cb = 0; cb < 512; ++cb) s += zpart[(size_t)cb * ROWS + t];
  invl[t] = 1.0f / s;
}

// prio[b,c] = comb[b] + 0.1 * sum_t exp(scores[b,t,c]) * invl1[b,t]
__global__ __launch_bounds__(256, 2) void k_usage(const ush* __restrict__ mhi,
                                                  const ush* __restrict__ mlo,
                                                  const ush* __restrict__ khi,
                                                  const ush* __restrict__ klo,
                                                  const float* __restrict__ invl,
                                                  const float* __restrict__ comb,
                                                  float* __restrict__ prio) {
  __shared__ ush Ahi[128 * 64], Alo[128 * 64], Bhi[128 * 64], Blo[128 * 64];
  const int tid = threadIdx.x;
  const int lane = tid & 63, w = tid >> 6;
  const int l15 = lane & 15, g = lane >> 4;
  const int cBase = blockIdx.x * 128;
  const int b = blockIdx.y;
  const ush* khb = khi + (size_t)b * Tn * Dn;
  const ush* klb = klo + (size_t)b * Tn * Dn;
  const int r0 = tid >> 3, u0 = tid & 7;
  const int usw = (u0 ^ (r0 & 7)) << 3;

  float uacc[2][4] = {{0.f, 0.f, 0.f, 0.f}, {0.f, 0.f, 0.f, 0.f}};
  for (int tt = 0; tt < 8; ++tt) {
    f32x4 S[2][8];
#pragma unroll
    for (int mi = 0; mi < 2; ++mi)
#pragma unroll
      for (int ni = 0; ni < 8; ++ni) S[mi][ni] = (f32x4){0.f, 0.f, 0.f, 0.f};
    for (int kk = 0; kk < 8; ++kk) {
      __syncthreads();
      {
        size_t a0 = (size_t)(cBase + r0) * Dn + kk * 64 + usw;
        size_t a1 = (size_t)(cBase + r0 + 64) * Dn + kk * 64 + usw;
        gl16(&mhi[a0], &Ahi[w * 512]);
        gl16(&mhi[a1], &Ahi[4096 + w * 512]);
        gl16(&mlo[a0], &Alo[w * 512]);
        gl16(&mlo[a1], &Alo[4096 + w * 512]);
        size_t b0 = (size_t)(tt * 128 + r0) * Dn + kk * 64 + usw;
        size_t b1 = (size_t)(tt * 128 + r0 + 64) * Dn + kk * 64 + usw;
        gl16(&khb[b0], &Bhi[w * 512]);
        gl16(&khb[b1], &Bhi[4096 + w * 512]);
        gl16(&klb[b0], &Blo[w * 512]);
        gl16(&klb[b1], &Blo[4096 + w * 512]);
      }
      __syncthreads();
#pragma unroll
      for (int ks2 = 0; ks2 < 2; ++ks2) {
        s16x8 ah[2], al[2];
#pragma unroll
        for (int mi = 0; mi < 2; ++mi) {
          int crow = w * 32 + mi * 16 + l15;
          int addr = crow * 64 + (((ks2 * 4 + g) ^ (crow & 7)) * 8);
          ah[mi] = *(const s16x8*)&Ahi[addr];
          al[mi] = *(const s16x8*)&Alo[addr];
        }
#pragma unroll
        for (int ni = 0; ni < 8; ++ni) {
          int trow = ni * 16 + l15;
          int addr = trow * 64 + (((ks2 * 4 + g) ^ (trow & 7)) * 8);
          s16x8 bh = *(const s16x8*)&Bhi[addr];
          s16x8 bl = *(const s16x8*)&Blo[addr];
#pragma unroll
          for (int mi = 0; mi < 2; ++mi) {
            S[mi][ni] = MFMA(ah[mi], bh, S[mi][ni]);
            S[mi][ni] = MFMA(ah[mi], bl, S[mi][ni]);
            S[mi][ni] = MFMA(al[mi], bh, S[mi][ni]);
          }
        }
      }
    }
#pragma unroll
    for (int ni = 0; ni < 8; ++ni) {
      float il = invl[b * Tn + tt * 128 + ni * 16 + l15];
#pragma unroll
      for (int mi = 0; mi < 2; ++mi)
#pragma unroll
        for (int r = 0; r < 4; ++r) uacc[mi][r] += __expf(S[mi][ni][r]) * il;
    }
  }
#pragma unroll
  for (int mi = 0; mi < 2; ++mi)
#pragma unroll
    for (int r = 0; r < 4; ++r) {
      float v = uacc[mi][r];
      v += __shfl_xor(v, 1);
      v += __shfl_xor(v, 2);
      v += __shfl_xor(v, 4);
      v += __shfl_xor(v, 8);
      if (l15 == 0)
        prio[(size_t)b * CAPn + cBase + w * 32 + mi * 16 + g * 4 + r] =
            comb[b] + 0.1f * v;
    }
}

// rank init: unselected slots get Kn (k_newmem tests r < Kn)
__global__ void k_rankinit(int* __restrict__ rank) {
  rank[blockIdx.x * 256 + threadIdx.x] = Kn;
}

// Per-batch exact top-K selection + stable rank (jax top_k semantics).
__global__ __launch_bounds__(1024) void k_select(const float* __restrict__ prio,
                                                 int* __restrict__ rank) {
  const int b = blockIdx.x;
  const float* p = prio + (size_t)b * CAPn;
  __shared__ int hist[256];
  __shared__ unsigned long long s_pref;
  __shared__ int s_krem;
  __shared__ int s_cnt;
  __shared__ unsigned long long selk[Kn];
  const int tid = threadIdx.x;
  if (tid == 0) { s_pref = 0ull; s_krem = Kn; s_cnt = 0; }

#define KEYOF(c, kk)                                                         \
  {                                                                          \
    unsigned mb_ = __float_as_uint(p[(c)]);                                  \
    mb_ = (mb_ & 0x80000000u) ? ~mb_ : (mb_ | 0x80000000u);                  \
    (kk) = ((unsigned long long)mb_ << 32) | (unsigned)(0xFFFFFFFFu - (c));  \
  }

  __syncthreads();
  for (int pos = 56; pos >= 0; pos -= 8) {
    if (tid < 256) hist[tid] = 0;
    __syncthreads();
    unsigned long long pref = s_pref;
    unsigned long long maskhi = (pos == 56) ? 0ull : (~0ull << (pos + 8));
    for (int c = tid; c < CAPn; c += 1024) {
      unsigned long long k;
      KEYOF(c, k);
      if ((k & maskhi) == pref) atomicAdd(&hist[(int)((k >> pos) & 255)], 1);
    }
    __syncthreads();
    if (tid == 0) {
      int krem = s_krem;
      int d = 255;
      for (;; --d) {
        int h = hist[d];
        if (krem <= h || d == 0) break;
        krem -= h;
      }
      s_pref = pref | ((unsigned long long)d << pos);
      s_krem = krem;
    }
    __syncthreads();
  }
  unsigned long long T = s_pref;  // exact Kn-th largest key
  for (int c = tid; c < CAPn; c += 1024) {
    unsigned long long k;
    KEYOF(c, k);
    if (k >= T) {
      int idx = atomicAdd(&s_cnt, 1);
      selk[idx] = k;
    }
  }
  __syncthreads();
  unsigned long long mine = selk[tid];
  int r = 0;
  for (int j = 0; j < Kn; ++j) r += (selk[j] > mine) ? 1 : 0;
  int c = (int)(0xFFFFFFFFu - (unsigned)(mine & 0xFFFFFFFFull));
  rank[(size_t)b * CAPn + c] = r;
#undef KEYOF
}

// new_mem (bf16) = 0.99*mem + 0.0025 * sum_b (rank_b[c] < K ? values[b, rank_b[c], :] : 0)
__global__ void k_newmem(const float* __restrict__ mem, const float* __restrict__ values,
                         const int* __restrict__ rank, ush* __restrict__ nm) {
  int gid = blockIdx.x * 256 + threadIdx.x;
  int c = gid >> 7;
  int q = (gid & 127) << 2;
  f32x4 m = *(const f32x4*)&mem[(size_t)c * Dn + q];
  f32x4 acc = {0.f, 0.f, 0.f, 0.f};
#pragma unroll
  for (int b = 0; b < Bn; ++b) {
    int r = rank[(size_t)b * CAPn + c];
    if (r < Kn) acc += *(const f32x4*)&values[((size_t)b * Tn + r) * Dn + q];
  }
  f32x4 res = m * MOM + acc * RATE_B;
  s16x4 o;
#pragma unroll
  for (int j = 0; j < 4; ++j) o[j] = (short)bfrn(res[j]);
  *(s16x4*)&nm[(size_t)c * Dn + q] = o;
}

// nmT[d][c] = nm[c][d]
__global__ void k_nmT(const ush* __restrict__ nm, ush* __restrict__ nmT) {
  __shared__ ush tile[64][65];
  int cBase = blockIdx.x * 64, dBase = blockIdx.y * 64;
  int tid = threadIdx.x;
#pragma unroll
  for (int rr = 0; rr < 2; ++rr) {
    int idx = rr * 256 + tid;
    int row = idx >> 3, ch = idx & 7;
    s16x8 v = *(const s16x8*)&nm[(size_t)(cBase + row) * Dn + dBase + ch * 8];
#pragma unroll
    for (int j = 0; j < 8; ++j) tile[row][ch * 8 + j] = (ush)v[j];
  }
  __syncthreads();
#pragma unroll
  for (int rr = 0; rr < 2; ++rr) {
    int idx = rr * 256 + tid;
    int drow = idx >> 3, ch = idx & 7;
    s16x8 v;
#pragma unroll
    for (int j = 0; j < 8; ++j) v[j] = (short)tile[ch * 8 + j][drow];
    *(s16x8*)&nmT[(size_t)(dBase + drow) * CAPn + cBase + ch * 8] = v;
  }
}

// Fused attn, LDS-traffic-minimized decomposition:
//   Block = 64 q x 8192 c (grid 4 cy x 64 qt), 8 waves.
//   QK: waves = 4 c-quarters (cs) x 2 q-halves (qg); wave tile 32c x 32q,
//       Q in regs (qfr[2][16], 32 q full-K). M-rows read 2x (was 8x).
//   PV: waves own disjoint 64-d slabs x all 64 q; Mt chunks [512 d][32 c],
//       zero read redundancy (was 8x). O = 4x4 frags (64 VGPR).
//   Sync: round-5 style (stage -> compute -> __syncthreads per phase; dbuf[2]
//   per stream, depth-1) -- proven WAR/RAW-safe; scheduling was not the limiter.
// LDS (ush idx): Ms[2][128][64] @0 (32KB), Mt[2][512][32] @16384 (64KB),
//                Ps[64][128] @49152 (16KB). Epilogue reuses Mt as [64 q][512 d].
__global__ __launch_bounds__(512) void k_attnout(
    const float* __restrict__ query, const ush* __restrict__ nm,
    const ush* __restrict__ nmT, ush* __restrict__ opart,
    float* __restrict__ zp2) {
  __shared__ ush lds[57344];
  __shared__ float zredw[4][64];
  __shared__ float zacc[64];
  constexpr int LMS = 0, LMT = 16384, LPS = 49152;
  const int tid = threadIdx.x;
  const int lane = tid & 63, w = tid >> 6;
  const int l15 = lane & 15, g = lane >> 4;
  const int cs = w & 3, qg = w >> 2;
  const int cy = blockIdx.x;
  const int qBase = blockIdx.y * 64;
  const int r0 = tid >> 3, u0 = tid & 7;
  const int usw = (u0 ^ (r0 & 7)) << 3;

  auto stage_ms = [&](int buf, int cb_, int kk) {
    const ush* src = nm + (size_t)cb_ * Dn + kk * 64;
    gl16(&src[(size_t)r0 * Dn + usw], &lds[LMS + buf * 8192 + w * 512]);
    gl16(&src[(size_t)(r0 + 64) * Dn + usw], &lds[LMS + buf * 8192 + 4096 + w * 512]);
  };
  // Mt chunk [512 d][32 c]; unit (16B) XOR-swizzled by (d&3) on both sides.
  auto stage_mt = [&](int buf, int cb_, int pcT) {
    const int cc = cb_ + pcT * 32;
    const int cu = tid & 3;
#pragma unroll
    for (int j = 0; j < 4; ++j) {
      int d = (j * 512 + tid) >> 2;
      gl16(&nmT[(size_t)d * CAPn + cc + ((cu ^ (d & 3)) << 3)],
           &lds[LMT + buf * 16384 + (j * 512 + w * 64) * 8]);
    }
  };

  // Q fragments in registers: wave's 32 q rows, full K=512, converted once.
  s16x8 qfr[2][16];
#pragma unroll
  for (int ni = 0; ni < 2; ++ni) {
    const float* qsrc = query + (size_t)(qBase + qg * 32 + ni * 16 + l15) * Dn;
#pragma unroll
    for (int ks = 0; ks < 16; ++ks) {
      f32x4 a = *(const f32x4*)&qsrc[ks * 32 + g * 8];
      f32x4 b = *(const f32x4*)&qsrc[ks * 32 + g * 8 + 4];
      s16x8 h;
#pragma unroll
      for (int j = 0; j < 4; ++j) {
        h[j] = (short)bfrn(a[j]);
        h[4 + j] = (short)bfrn(b[j]);
      }
      qfr[ni][ks] = h;
    }
  }

  f32x4 O[4][4];  // O^T: d = w*64 + mi*16 + g*4 + r, q = ni*16 + l15
#pragma unroll
  for (int mi = 0; mi < 4; ++mi)
#pragma unroll
    for (int ni = 0; ni < 4; ++ni) O[mi][ni] = (f32x4){0.f, 0.f, 0.f, 0.f};
  if (tid < 64) zacc[tid] = 0.f;

  stage_ms(0, cy * 8192, 0);
  __syncthreads();

  for (int ct = 0; ct < 64; ++ct) {
    const int cBase = cy * 8192 + ct * 128;
    const int cNext = cy * 8192 + ((ct + 1) & 63) * 128;  // wrap: valid, unused

    // ---- QK phases kk=0..7: consume Ms[kk&1] ----
    f32x4 S[2][2];
#pragma unroll
    for (int mi = 0; mi < 2; ++mi)
#pragma unroll
      for (int ni = 0; ni < 2; ++ni) S[mi][ni] = (f32x4){0.f, 0.f, 0.f, 0.f};
#pragma unroll
    for (int kk = 0; kk < 8; ++kk) {
      if (kk < 7) stage_ms((kk + 1) & 1, cBase, kk + 1);
      else stage_mt(0, cBase, 0);  // Mt[0] for PV0
      __builtin_amdgcn_s_setprio(1);
#pragma unroll
      for (int ks2 = 0; ks2 < 2; ++ks2) {
        s16x8 am[2];
#pragma unroll
        for (int mi = 0; mi < 2; ++mi) {
          int row = cs * 32 + mi * 16 + l15;
          am[mi] = *(const s16x8*)&lds[LMS + (kk & 1) * 8192 + row * 64 +
                                       (((ks2 * 4 + g) ^ (row & 7)) << 3)];
        }
#pragma unroll
        for (int mi = 0; mi < 2; ++mi)
#pragma unroll
          for (int ni = 0; ni < 2; ++ni)
            S[mi][ni] = MFMA(am[mi], qfr[ni][kk * 2 + ks2], S[mi][ni]);
      }
      __builtin_amdgcn_s_setprio(0);
      __syncthreads();
    }

    // ---- P phase: exp(S*SCALE) -> Ps (unnormalized); z partials ----
    stage_mt(1, cBase, 1);  // Mt[1] for PV1
    {
      float zl[2] = {0.f, 0.f};
#pragma unroll
      for (int ni = 0; ni < 2; ++ni) {
        int q = qg * 32 + ni * 16 + l15;
#pragma unroll
        for (int mi = 0; mi < 2; ++mi) {
          s16x4 p;
#pragma unroll
          for (int r = 0; r < 4; ++r) {
            float e = __expf(S[mi][ni][r] * SCALE);
            zl[ni] += e;
            p[r] = (short)bfrn(e);
          }
          int u16 = (cs * 4 + mi * 2 + (g >> 1)) ^ (q & 15);
          *(s16x4*)&lds[LPS + q * 128 + u16 * 8 + (g & 1) * 4] = p;
        }
        float v = zl[ni];
        v += __shfl_xor(v, 16);
        v += __shfl_xor(v, 32);
        if (g == 0) zredw[cs][q] = v;
      }
    }
    __syncthreads();

    // ---- PV phases pc=0..3: consume Mt[pc&1]; wave owns d-slab w*64.. ----
#pragma unroll
    for (int pc = 0; pc < 4; ++pc) {
      if (pc == 0) {
        if (tid < 64)
          zacc[tid] += (zredw[0][tid] + zredw[1][tid]) + (zredw[2][tid] + zredw[3][tid]);
      } else if (pc == 1) stage_mt(0, cBase, 2);
      else if (pc == 2) stage_mt(1, cBase, 3);
      else stage_ms(0, cNext, 0);  // next ct QK0
      __builtin_amdgcn_s_setprio(1);
      s16x8 am[4], pb[4];
#pragma unroll
      for (int mi = 0; mi < 4; ++mi) {
        int drow = w * 64 + mi * 16 + l15;
        am[mi] = *(const s16x8*)&lds[LMT + (pc & 1) * 16384 + drow * 32 +
                                     ((g ^ (drow & 3)) << 3)];
      }
#pragma unroll
      for (int ni = 0; ni < 4; ++ni) {
        int q = ni * 16 + l15;
        int u16 = (pc * 4 + g) ^ (q & 15);
        pb[ni] = *(const s16x8*)&lds[LPS + q * 128 + u16 * 8];
      }
#pragma unroll
      for (int mi = 0; mi < 4; ++mi)
#pragma unroll
        for (int ni = 0; ni < 4; ++ni) O[mi][ni] = MFMA(am[mi], pb[ni], O[mi][ni]);
      __builtin_amdgcn_s_setprio(0);
      __syncthreads();
    }
  }

  // ---- epilogue: z store + O transpose via Mt region ([64 q][512 d]) ----
  if (tid < 64) zp2[(size_t)cy * ROWS + qBase + tid] = zacc[tid];
#pragma unroll
  for (int mi = 0; mi < 4; ++mi)
#pragma unroll
    for (int ni = 0; ni < 4; ++ni) {
      s16x4 ov;
#pragma unroll
      for (int r = 0; r < 4; ++r) ov[r] = (short)bfrn(O[mi][ni][r]);
      int q = ni * 16 + l15;
      int us = (w * 8 + mi * 2 + (g >> 1)) ^ (q & 7);
      *(s16x4*)&lds[LMT + q * 512 + us * 8 + (g & 1) * 4] = ov;
    }
  __syncthreads();
#pragma unroll
  for (int pass = 0; pass < 8; ++pass) {
    int q = pass * 8 + w, u = lane;
    s16x8 v = *(const s16x8*)&lds[LMT + q * 512 + ((u ^ (q & 7)) << 3)];
    *(s16x8*)&opart[((size_t)cy * ROWS + qBase + q) * Dn + u * 8] = v;
  }
}

// out = (sum_cy opart[cy]) / (sum_cy zp2[cy]) per row
__global__ void k_merge(const ush* __restrict__ opart, const float* __restrict__ zp2,
                        float* __restrict__ out) {
  size_t i = ((size_t)blockIdx.x * 256 + threadIdx.x) * 4;
  int row = (int)(i >> 9);
  float z = 0.f;
#pragma unroll
  for (int cyy = 0; cyy < 4; ++cyy) z += zp2[(size_t)cyy * ROWS + row];
  float inv = 1.0f / z;
  f32x4 acc = {0.f, 0.f, 0.f, 0.f};
#pragma unroll
  for (int cyy = 0; cyy < 4; ++cyy) {
    s16x4 a = *(const s16x4*)&opart[(size_t)cyy * ROWS * Dn + i];
#pragma unroll
    for (int j = 0; j < 4; ++j) acc[j] += bff((ush)a[j]);
  }
#pragma unroll
  for (int j = 0; j < 4; ++j) acc[j] *= inv;
  *(f32x4*)&out[i] = acc;
}

extern "C" void kernel_launch(void* const* d_in, const int* in_sizes, int n_in,
                              void* d_out, int out_size, void* d_ws, size_t ws_size,
                              hipStream_t stream) {
  const float* keys = (const float*)d_in[0];
  const float* values = (const float*)d_in[1];
  const float* importance = (const float*)d_in[2];
  const float* query = (const float*)d_in[3];
  const float* mem = (const float*)d_in[4];
  char* wsb = (char*)d_ws;
  ush* nm    = (ush*)(wsb + OFF_NM);
  ush* nmT   = (ush*)(wsb + OFF_NMT);
  ush* mlo   = (ush*)(wsb + OFF_NM);   // alias (dead after k_usage)
  ush* mhi   = (ush*)(wsb + OFF_NMT);  // alias (dead after k_usage)
  ush* khi   = (ush*)(wsb + OFF_KHI);
  ush* klo   = (ush*)(wsb + OFF_KLO);
  ush* opart = (ush*)(wsb + OFF_OPART);
  float* zpart = (float*)(wsb + OFF_ZPART);
  float* prio  = (float*)(wsb + OFF_PRIO);
  int* rank    = (int*)(wsb + OFF_RANK);
  float* comb  = (float*)(wsb + OFF_COMB);
  float* zp2   = (float*)(wsb + OFF_ZP2);
  float* invl1 = (float*)(wsb + OFF_COMB + 64);
  float* out = (float*)d_out;

  k_combined<<<Bn, 256, 0, stream>>>(importance, comb);
  k_cvt_hilo<<<(ROWS * Dn / 4) / 256, 256, 0, stream>>>(keys, khi, klo);
  k_cvt_hilo<<<(CAPn * Dn / 4) / 256, 256, 0, stream>>>(mem, mhi, mlo);
  k_rowexp<<<CAPn / 64, 256, 0, stream>>>(mhi, khi, zpart);
  k_invl<<<ROWS / 256, 256, 0, stream>>>(zpart, invl1);
  k_usage<<<dim3(CAPn / 128, Bn), 256, 0, stream>>>(mhi, mlo, khi, klo, invl1, comb, prio);
  k_rankinit<<<(Bn * CAPn) / 256, 256, 0, stream>>>(rank);
  k_select<<<Bn, 1024, 0, stream>>>(prio, rank);
  k_newmem<<<(CAPn * Dn / 4) / 256, 256, 0, stream>>>(mem, values, rank, nm);
  k_nmT<<<dim3(CAPn / 64, Dn / 64), 256, 0, stream>>>(nm, nmT);
  k_attnout<<<dim3(4, ROWS / 64), 512, 0, stream>>>(query, nm, nmT, opart, zp2);
  k_merge<<<(ROWS * Dn / 4) / 256, 256, 0, stream>>>(opart, zp2, out);
}

// Round 9
// 1015.243 us; speedup vs baseline: 1.3317x; 1.3317x over previous
//
#include <hip/hip_runtime.h>

typedef float f32x4 __attribute__((ext_vector_type(4)));
typedef short s16x8 __attribute__((ext_vector_type(8)));
typedef short s16x4 __attribute__((ext_vector_type(4)));
typedef unsigned short ush;

constexpr int Bn = 4, Tn = 1024, Dn = 512, CAPn = 32768, Kn = 1024;
constexpr int ROWS = Bn * Tn; // 4096
constexpr float SCALE = 0.044194173824159216f; // 1/sqrt(512)
constexpr float MOM = 0.99f;
constexpr float RATE_B = 0.0025f; // 0.01 / B

// ---- workspace layout (byte offsets). Total 100.79e6 B (proven ws >= 102.0e6 B) ----
constexpr size_t OFF_NM    = 0;                      // bf16 [CAP][D] (late)
constexpr size_t OFF_NMT   = 33554432;               // bf16 [D][CAP] (alias: mem f16 early)
constexpr size_t OFF_OPART = 67108864;               // bf16 [8][ROWS][D] (late)  -- UNION with:
constexpr size_t OFF_KHF   = 67108864;               //   f16 [ROWS][D] (early)
constexpr size_t OFF_ZPART = 75497472;               //   f32 [512][ROWS] (early)
constexpr size_t OFF_PRIO  = 83886080;               //   f32 [4][CAP] (early)
constexpr size_t OFF_RANK  = 84410368;               //   i32 [4][CAP] (early)
constexpr size_t OFF_COMB  = 84934656;               //   f32 [4] (early; +64: invl1)
constexpr size_t OFF_ZP2   = 100663296;              // f32 [8][ROWS] (late)

#define MFMA(a, b, c) __builtin_amdgcn_mfma_f32_16x16x32_bf16((a), (b), (c), 0, 0, 0)
#define MFMAH(a, b, c) __builtin_amdgcn_mfma_f32_16x16x32_f16((a), (b), (c), 0, 0, 0)

__device__ __forceinline__ ush bfrn(float x) {
  unsigned u = __float_as_uint(x);
  return (ush)((u + 0x7FFFu + ((u >> 16) & 1u)) >> 16);
}
__device__ __forceinline__ float bff(ush h) { return __uint_as_float(((unsigned)h) << 16); }
__device__ __forceinline__ ush f16rn(float x) {
  _Float16 h = (_Float16)x;  // v_cvt_f16_f32, RTN
  return *(ush*)&h;
}

__device__ __forceinline__ void gl16(const ush* g, ush* l) {
  __builtin_amdgcn_global_load_lds(
      (const __attribute__((address_space(1))) void*)(uintptr_t)g,
      (__attribute__((address_space(3))) void*)(uintptr_t)l, 16, 0, 0);
}

// combined[b] = mean(importance[b,:,0])
__global__ void k_combined(const float* __restrict__ imp, float* __restrict__ comb) {
  __shared__ float red[256];
  int b = blockIdx.x;
  float s = 0.f;
  for (int t = threadIdx.x; t < Tn; t += 256) s += imp[(size_t)b * Tn + t];
  red[threadIdx.x] = s;
  __syncthreads();
  for (int off = 128; off > 0; off >>= 1) {
    if (threadIdx.x < (unsigned)off) red[threadIdx.x] += red[threadIdx.x + off];
    __syncthreads();
  }
  if (threadIdx.x == 0) comb[b] = red[0] * (1.0f / Tn);
}

// x -> f16 (RTN). 4 elems/thread.
__global__ void k_cvt_f16(const float* __restrict__ x, ush* __restrict__ o) {
  size_t i = ((size_t)blockIdx.x * 256 + threadIdx.x) * 4;
  f32x4 v = *(const f32x4*)&x[i];
  s16x4 h;
#pragma unroll
  for (int j = 0; j < 4; ++j) h[j] = (short)f16rn(v[j]);
  *(s16x4*)&o[i] = h;
}

// Z partials: zpart[cb][t] = sum over this block's 64 c of exp(A[c,:].B[t,:])
// f16 inputs, f16 MFMA. A rows in registers; B staged via gl16.
__global__ __launch_bounds__(256, 2) void k_rowexp(const ush* __restrict__ Ahf,
                                                   const ush* __restrict__ Bhf,
                                                   float* __restrict__ zpart) {
  __shared__ ush Bs[64 * 512];
  __shared__ float red[2][64];
  const int tid = threadIdx.x;
  const int lane = tid & 63, wid = tid >> 6;
  const int wc2 = wid >> 1, wt = wid & 1;
  const int l15 = lane & 15, g = lane >> 4;
  const int cb = blockIdx.x;
  const int cBase = cb * 64;

  s16x8 afr[2][16];
#pragma unroll
  for (int mi = 0; mi < 2; ++mi) {
    int c = cBase + wc2 * 32 + mi * 16 + l15;
#pragma unroll
    for (int ks = 0; ks < 16; ++ks)
      afr[mi][ks] = *(const s16x8*)&Ahf[(size_t)c * Dn + ks * 32 + g * 8];
  }

  for (int tt = 0; tt < 64; ++tt) {
    const int tBase = tt * 64;
#pragma unroll
    for (int rr = 0; rr < 16; ++rr) {
      int idx = rr * 256 + tid;
      int row = idx >> 6, ch = idx & 63;
      gl16(&Bhf[(size_t)(tBase + row) * Dn + ((ch ^ (row & 7)) << 3)],
           &Bs[rr * 2048 + wid * 512]);
    }
    __syncthreads();
    f32x4 S[2][2];
#pragma unroll
    for (int mi = 0; mi < 2; ++mi)
#pragma unroll
      for (int ni = 0; ni < 2; ++ni) S[mi][ni] = (f32x4){0.f, 0.f, 0.f, 0.f};
#pragma unroll
    for (int ks = 0; ks < 16; ++ks) {
      s16x8 bfr[2];
#pragma unroll
      for (int ni = 0; ni < 2; ++ni) {
        int trow = wt * 32 + ni * 16 + l15;
        bfr[ni] = *(const s16x8*)&Bs[trow * 512 + (((ks * 4 + g) ^ (trow & 7)) * 8)];
      }
#pragma unroll
      for (int mi = 0; mi < 2; ++mi)
#pragma unroll
        for (int ni = 0; ni < 2; ++ni) S[mi][ni] = MFMAH(afr[mi][ks], bfr[ni], S[mi][ni]);
    }
    float tacc[2] = {0.f, 0.f};
#pragma unroll
    for (int mi = 0; mi < 2; ++mi)
#pragma unroll
      for (int ni = 0; ni < 2; ++ni)
#pragma unroll
        for (int r = 0; r < 4; ++r) tacc[ni] += __expf(S[mi][ni][r]);
#pragma unroll
    for (int ni = 0; ni < 2; ++ni) {
      float v = tacc[ni];
      v += __shfl_xor(v, 16);
      v += __shfl_xor(v, 32);
      tacc[ni] = v;
    }
    if (g == 0) {
      red[wc2][wt * 32 + l15] = tacc[0];
      red[wc2][wt * 32 + 16 + l15] = tacc[1];
    }
    __syncthreads();
    if (tid < 64) zpart[(size_t)cb * ROWS + tBase + tid] = red[0][tid] + red[1][tid];
  }
}

__global__ void k_invl(const float* __restrict__ zpart, float* __restrict__ invl) {
  int t = blockIdx.x * 256 + threadIdx.x;
  float s = 0.f;
  for (int cb = 0; cb < 512; ++cb) s += zpart[(size_t)cb * ROWS + t];
  invl[t] = 1.0f / s;
}

// prio[b,c] = comb[b] + 0.1 * sum_t exp(scores[b,t,c]) * invl1[b,t]
// Single-term f16 MFMA (f16 rounding 2^-11 keeps top-k selection stable).
__global__ __launch_bounds__(256, 2) void k_usage(const ush* __restrict__ mhf,
                                                  const ush* __restrict__ khf,
                                                  const float* __restrict__ invl,
                                                  const float* __restrict__ comb,
                                                  float* __restrict__ prio) {
  __shared__ ush Ah[128 * 64], Bh[128 * 64];
  const int tid = threadIdx.x;
  const int lane = tid & 63, w = tid >> 6;
  const int l15 = lane & 15, g = lane >> 4;
  const int cBase = blockIdx.x * 128;
  const int b = blockIdx.y;
  const ush* khb = khf + (size_t)b * Tn * Dn;
  const int r0 = tid >> 3, u0 = tid & 7;
  const int usw = (u0 ^ (r0 & 7)) << 3;

  float uacc[2][4] = {{0.f, 0.f, 0.f, 0.f}, {0.f, 0.f, 0.f, 0.f}};
  for (int tt = 0; tt < 8; ++tt) {
    f32x4 S[2][8];
#pragma unroll
    for (int mi = 0; mi < 2; ++mi)
#pragma unroll
      for (int ni = 0; ni < 8; ++ni) S[mi][ni] = (f32x4){0.f, 0.f, 0.f, 0.f};
    for (int kk = 0; kk < 8; ++kk) {
      __syncthreads();
      {
        size_t a0 = (size_t)(cBase + r0) * Dn + kk * 64 + usw;
        size_t a1 = (size_t)(cBase + r0 + 64) * Dn + kk * 64 + usw;
        gl16(&mhf[a0], &Ah[w * 512]);
        gl16(&mhf[a1], &Ah[4096 + w * 512]);
        size_t b0 = (size_t)(tt * 128 + r0) * Dn + kk * 64 + usw;
        size_t b1 = (size_t)(tt * 128 + r0 + 64) * Dn + kk * 64 + usw;
        gl16(&khb[b0], &Bh[w * 512]);
        gl16(&khb[b1], &Bh[4096 + w * 512]);
      }
      __syncthreads();
#pragma unroll
      for (int ks2 = 0; ks2 < 2; ++ks2) {
        s16x8 ah[2];
#pragma unroll
        for (int mi = 0; mi < 2; ++mi) {
          int crow = w * 32 + mi * 16 + l15;
          ah[mi] = *(const s16x8*)&Ah[crow * 64 + (((ks2 * 4 + g) ^ (crow & 7)) * 8)];
        }
#pragma unroll
        for (int ni = 0; ni < 8; ++ni) {
          int trow = ni * 16 + l15;
          s16x8 bh = *(const s16x8*)&Bh[trow * 64 + (((ks2 * 4 + g) ^ (trow & 7)) * 8)];
#pragma unroll
          for (int mi = 0; mi < 2; ++mi) S[mi][ni] = MFMAH(ah[mi], bh, S[mi][ni]);
        }
      }
    }
#pragma unroll
    for (int ni = 0; ni < 8; ++ni) {
      float il = invl[b * Tn + tt * 128 + ni * 16 + l15];
#pragma unroll
      for (int mi = 0; mi < 2; ++mi)
#pragma unroll
        for (int r = 0; r < 4; ++r) uacc[mi][r] += __expf(S[mi][ni][r]) * il;
    }
  }
#pragma unroll
  for (int mi = 0; mi < 2; ++mi)
#pragma unroll
    for (int r = 0; r < 4; ++r) {
      float v = uacc[mi][r];
      v += __shfl_xor(v, 1);
      v += __shfl_xor(v, 2);
      v += __shfl_xor(v, 4);
      v += __shfl_xor(v, 8);
      if (l15 == 0)
        prio[(size_t)b * CAPn + cBase + w * 32 + mi * 16 + g * 4 + r] =
            comb[b] + 0.1f * v;
    }
}

// rank init: unselected slots get Kn (k_newmem tests r < Kn)
__global__ void k_rankinit(int* __restrict__ rank) {
  rank[blockIdx.x * 256 + threadIdx.x] = Kn;
}

// Per-batch exact top-K selection + stable rank (jax top_k semantics).
__global__ __launch_bounds__(1024) void k_select(const float* __restrict__ prio,
                                                 int* __restrict__ rank) {
  const int b = blockIdx.x;
  const float* p = prio + (size_t)b * CAPn;
  __shared__ int hist[256];
  __shared__ unsigned long long s_pref;
  __shared__ int s_krem;
  __shared__ int s_cnt;
  __shared__ unsigned long long selk[Kn];
  const int tid = threadIdx.x;
  if (tid == 0) { s_pref = 0ull; s_krem = Kn; s_cnt = 0; }

#define KEYOF(c, kk)                                                         \
  {                                                                          \
    unsigned mb_ = __float_as_uint(p[(c)]);                                  \
    mb_ = (mb_ & 0x80000000u) ? ~mb_ : (mb_ | 0x80000000u);                  \
    (kk) = ((unsigned long long)mb_ << 32) | (unsigned)(0xFFFFFFFFu - (c));  \
  }

  __syncthreads();
  for (int pos = 56; pos >= 0; pos -= 8) {
    if (tid < 256) hist[tid] = 0;
    __syncthreads();
    unsigned long long pref = s_pref;
    unsigned long long maskhi = (pos == 56) ? 0ull : (~0ull << (pos + 8));
    for (int c = tid; c < CAPn; c += 1024) {
      unsigned long long k;
      KEYOF(c, k);
      if ((k & maskhi) == pref) atomicAdd(&hist[(int)((k >> pos) & 255)], 1);
    }
    __syncthreads();
    if (tid == 0) {
      int krem = s_krem;
      int d = 255;
      for (;; --d) {
        int h = hist[d];
        if (krem <= h || d == 0) break;
        krem -= h;
      }
      s_pref = pref | ((unsigned long long)d << pos);
      s_krem = krem;
    }
    __syncthreads();
  }
  unsigned long long T = s_pref;  // exact Kn-th largest key
  for (int c = tid; c < CAPn; c += 1024) {
    unsigned long long k;
    KEYOF(c, k);
    if (k >= T) {
      int idx = atomicAdd(&s_cnt, 1);
      selk[idx] = k;
    }
  }
  __syncthreads();
  unsigned long long mine = selk[tid];
  int r = 0;
  for (int j = 0; j < Kn; ++j) r += (selk[j] > mine) ? 1 : 0;
  int c = (int)(0xFFFFFFFFu - (unsigned)(mine & 0xFFFFFFFFull));
  rank[(size_t)b * CAPn + c] = r;
#undef KEYOF
}

// new_mem (bf16) = 0.99*mem + 0.0025 * sum_b (rank_b[c] < K ? values[b, rank_b[c], :] : 0)
__global__ void k_newmem(const float* __restrict__ mem, const float* __restrict__ values,
                         const int* __restrict__ rank, ush* __restrict__ nm) {
  int gid = blockIdx.x * 256 + threadIdx.x;
  int c = gid >> 7;
  int q = (gid & 127) << 2;
  f32x4 m = *(const f32x4*)&mem[(size_t)c * Dn + q];
  f32x4 acc = {0.f, 0.f, 0.f, 0.f};
#pragma unroll
  for (int b = 0; b < Bn; ++b) {
    int r = rank[(size_t)b * CAPn + c];
    if (r < Kn) acc += *(const f32x4*)&values[((size_t)b * Tn + r) * Dn + q];
  }
  f32x4 res = m * MOM + acc * RATE_B;
  s16x4 o;
#pragma unroll
  for (int j = 0; j < 4; ++j) o[j] = (short)bfrn(res[j]);
  *(s16x4*)&nm[(size_t)c * Dn + q] = o;
}

// nmT[d][c] = nm[c][d]
__global__ void k_nmT(const ush* __restrict__ nm, ush* __restrict__ nmT) {
  __shared__ ush tile[64][65];
  int cBase = blockIdx.x * 64, dBase = blockIdx.y * 64;
  int tid = threadIdx.x;
#pragma unroll
  for (int rr = 0; rr < 2; ++rr) {
    int idx = rr * 256 + tid;
    int row = idx >> 3, ch = idx & 7;
    s16x8 v = *(const s16x8*)&nm[(size_t)(cBase + row) * Dn + dBase + ch * 8];
#pragma unroll
    for (int j = 0; j < 8; ++j) tile[row][ch * 8 + j] = (ush)v[j];
  }
  __syncthreads();
#pragma unroll
  for (int rr = 0; rr < 2; ++rr) {
    int idx = rr * 256 + tid;
    int drow = idx >> 3, ch = idx & 7;
    s16x8 v;
#pragma unroll
    for (int j = 0; j < 8; ++j) v[j] = (short)tile[ch * 8 + j][drow];
    *(s16x8*)&nmT[(size_t)(dBase + drow) * CAPn + cBase + ch * 8] = v;
  }
}

// Fused attn (round-7 version, 431 us, proven): counted-vmcnt pipeline,
// WAR-safe (stage issued post-BAR). Grid (8 cy, 32 qt), 8 waves, Q in regs.
// LDS 131KB: Ms[3][128][64] @0, Mt[3][128][64] @24576, Ps[128][128] @49152.
#define WAITV2 asm volatile("s_waitcnt vmcnt(2)" ::: "memory")
#define WAITL0 asm volatile("s_waitcnt lgkmcnt(0)" ::: "memory")
#define BAR __builtin_amdgcn_s_barrier()
__global__ __launch_bounds__(512, 1) void k_attnout(
    const float* __restrict__ query, const ush* __restrict__ nm,
    const ush* __restrict__ nmT, ush* __restrict__ opart,
    float* __restrict__ zp2) {
  __shared__ ush lds[65536];
  __shared__ float zred[128];
  __shared__ float zacc[128];
  constexpr int LMS = 0, LMT = 24576, LPS = 49152;
  const int tid = threadIdx.x;
  const int lane = tid & 63, w = tid >> 6;
  const int l15 = lane & 15, g = lane >> 4;
  const int cy = blockIdx.x;
  const int qBase = blockIdx.y * 128;
  const int q = w * 16 + l15;
  const int r0 = tid >> 3, u0 = tid & 7;
  const int usw = (u0 ^ (r0 & 7)) << 3;

  auto stage_ms = [&](int buf, int cb_, int kk) {
    const ush* src = nm + (size_t)cb_ * Dn + kk * 64;
    gl16(&src[(size_t)r0 * Dn + usw], &lds[LMS + buf * 8192 + w * 512]);
    gl16(&src[(size_t)(r0 + 64) * Dn + usw], &lds[LMS + buf * 8192 + 4096 + w * 512]);
  };
  auto stage_mt = [&](int buf, int cb_, int u) {
    const ush* src = nmT + (size_t)((u >> 1) * 128) * CAPn + cb_ + (u & 1) * 64;
    gl16(&src[(size_t)r0 * CAPn + usw], &lds[LMT + buf * 8192 + w * 512]);
    gl16(&src[(size_t)(r0 + 64) * CAPn + usw], &lds[LMT + buf * 8192 + 4096 + w * 512]);
  };

  s16x8 qfr[16];
  {
    const float* qsrc = query + (size_t)(qBase + q) * Dn;
#pragma unroll
    for (int ks = 0; ks < 16; ++ks) {
      f32x4 a = *(const f32x4*)&qsrc[ks * 32 + g * 8];
      f32x4 b = *(const f32x4*)&qsrc[ks * 32 + g * 8 + 4];
      s16x8 h;
#pragma unroll
      for (int j = 0; j < 4; ++j) {
        h[j] = (short)bfrn(a[j]);
        h[4 + j] = (short)bfrn(b[j]);
      }
      qfr[ks] = h;
    }
  }

  f32x4 O[32];
#pragma unroll
  for (int i = 0; i < 32; ++i) O[i] = (f32x4){0.f, 0.f, 0.f, 0.f};
  if (tid < 128) zacc[tid] = 0.f;

  stage_ms(0, cy * 4096, 0);
  stage_ms(1, cy * 4096, 1);

  for (int ct = 0; ct < 32; ++ct) {
    const int cBase = cy * 4096 + ct * 128;
    const int cNext = cy * 4096 + ((ct + 1) & 31) * 128;

    f32x4 S[8];
#pragma unroll
    for (int i = 0; i < 8; ++i) S[i] = (f32x4){0.f, 0.f, 0.f, 0.f};
#pragma unroll
    for (int kk = 0; kk < 8; ++kk) {
      WAITV2;
      WAITL0;
      BAR;
      if (kk < 6) stage_ms((kk + 2) % 3, cBase, kk + 2);
      else if (kk == 6) stage_mt(0, cBase, 0);
      else stage_mt(1, cBase, 1);
      __builtin_amdgcn_s_setprio(1);
#pragma unroll
      for (int ks2 = 0; ks2 < 2; ++ks2) {
#pragma unroll
        for (int mi = 0; mi < 8; ++mi) {
          int row = mi * 16 + l15;
          s16x8 am = *(const s16x8*)&lds[LMS + (kk % 3) * 8192 + row * 64 +
                                         (((ks2 * 4 + g) ^ (row & 7)) << 3)];
          S[mi] = MFMA(am, qfr[kk * 2 + ks2], S[mi]);
        }
      }
      __builtin_amdgcn_s_setprio(0);
    }

    float zl = 0.f;
#pragma unroll
    for (int mi = 0; mi < 8; ++mi) {
      s16x4 p;
#pragma unroll
      for (int r = 0; r < 4; ++r) {
        float e = __expf(S[mi][r] * SCALE);
        zl += e;
        p[r] = (short)bfrn(e);
      }
      int u16 = (mi * 2 + (g >> 1)) ^ l15;
      *(s16x4*)&lds[LPS + q * 128 + u16 * 8 + (g & 1) * 4] = p;
    }
    zl += __shfl_xor(zl, 16);
    zl += __shfl_xor(zl, 32);
    if (g == 0) zred[q] = zl;
    WAITL0;
    BAR;
    if (tid < 128) zacc[tid] += zred[tid];

#pragma unroll
    for (int u = 0; u < 8; ++u) {
      WAITV2;
      WAITL0;
      BAR;
      if (u < 6) stage_mt((u + 2) % 3, cBase, u + 2);
      else if (u == 6) stage_ms(0, cNext, 0);
      else stage_ms(1, cNext, 1);
      __builtin_amdgcn_s_setprio(1);
      const int hh = u & 1;
#pragma unroll
      for (int kc = 0; kc < 2; ++kc) {
        int u16 = (hh * 8 + kc * 4 + g) ^ l15;
        s16x8 pb = *(const s16x8*)&lds[LPS + q * 128 + u16 * 8];
#pragma unroll
        for (int mi = 0; mi < 8; ++mi) {
          int row = mi * 16 + l15;
          s16x8 am = *(const s16x8*)&lds[LMT + (u % 3) * 8192 + row * 64 +
                                         (((kc * 4 + g) ^ (row & 7)) << 3)];
          O[(u >> 1) * 8 + mi] = MFMA(am, pb, O[(u >> 1) * 8 + mi]);
        }
      }
      __builtin_amdgcn_s_setprio(0);
    }
  }

  __syncthreads();
  if (tid < 128) zp2[(size_t)cy * ROWS + qBase + tid] = zacc[tid];
#pragma unroll
  for (int ds = 0; ds < 4; ++ds) {
    __syncthreads();
#pragma unroll
    for (int mi = 0; mi < 8; ++mi) {
      s16x4 ov;
#pragma unroll
      for (int r = 0; r < 4; ++r) ov[r] = (short)bfrn(O[ds * 8 + mi][r]);
      int u16 = (mi * 2 + (g >> 1)) ^ l15;
      *(s16x4*)&lds[LPS + q * 128 + u16 * 8 + (g & 1) * 4] = ov;
    }
    __syncthreads();
#pragma unroll
    for (int i = 0; i < 4; ++i) {
      int slot = i * 512 + tid;
      int qq = slot >> 4, u16 = slot & 15;
      s16x8 v = *(const s16x8*)&lds[LPS + qq * 128 + ((u16 ^ (qq & 15)) << 3)];
      *(s16x8*)&opart[((size_t)cy * ROWS + qBase + qq) * Dn + ds * 128 + u16 * 8] = v;
    }
  }
}

// out = (sum_cy opart[cy]) / (sum_cy zp2[cy]) per row
__global__ void k_merge(const ush* __restrict__ opart, const float* __restrict__ zp2,
                        float* __restrict__ out) {
  size_t i = ((size_t)blockIdx.x * 256 + threadIdx.x) * 4;
  int row = (int)(i >> 9);
  float z = 0.f;
#pragma unroll
  for (int cyy = 0; cyy < 8; ++cyy) z += zp2[(size_t)cyy * ROWS + row];
  float inv = 1.0f / z;
  f32x4 acc = {0.f, 0.f, 0.f, 0.f};
#pragma unroll
  for (int cyy = 0; cyy < 8; ++cyy) {
    s16x4 a = *(const s16x4*)&opart[(size_t)cyy * ROWS * Dn + i];
#pragma unroll
    for (int j = 0; j < 4; ++j) acc[j] += bff((ush)a[j]);
  }
#pragma unroll
  for (int j = 0; j < 4; ++j) acc[j] *= inv;
  *(f32x4*)&out[i] = acc;
}

extern "C" void kernel_launch(void* const* d_in, const int* in_sizes, int n_in,
                              void* d_out, int out_size, void* d_ws, size_t ws_size,
                              hipStream_t stream) {
  const float* keys = (const float*)d_in[0];
  const float* values = (const float*)d_in[1];
  const float* importance = (const float*)d_in[2];
  const float* query = (const float*)d_in[3];
  const float* mem = (const float*)d_in[4];
  char* wsb = (char*)d_ws;
  ush* nm    = (ush*)(wsb + OFF_NM);
  ush* nmT   = (ush*)(wsb + OFF_NMT);
  ush* mhf   = (ush*)(wsb + OFF_NMT);  // alias (dead after k_usage; nmT written later)
  ush* khf   = (ush*)(wsb + OFF_KHF);
  ush* opart = (ush*)(wsb + OFF_OPART);
  float* zpart = (float*)(wsb + OFF_ZPART);
  float* prio  = (float*)(wsb + OFF_PRIO);
  int* rank    = (int*)(wsb + OFF_RANK);
  float* comb  = (float*)(wsb + OFF_COMB);
  float* zp2   = (float*)(wsb + OFF_ZP2);
  float* invl1 = (float*)(wsb + OFF_COMB + 64);
  float* out = (float*)d_out;

  k_combined<<<Bn, 256, 0, stream>>>(importance, comb);
  k_cvt_f16<<<(ROWS * Dn / 4) / 256, 256, 0, stream>>>(keys, khf);
  k_cvt_f16<<<(CAPn * Dn / 4) / 256, 256, 0, stream>>>(mem, mhf);
  k_rowexp<<<CAPn / 64, 256, 0, stream>>>(mhf, khf, zpart);
  k_invl<<<ROWS / 256, 256, 0, stream>>>(zpart, invl1);
  k_usage<<<dim3(CAPn / 128, Bn), 256, 0, stream>>>(mhf, khf, invl1, comb, prio);
  k_rankinit<<<(Bn * CAPn) / 256, 256, 0, stream>>>(rank);
  k_select<<<Bn, 1024, 0, stream>>>(prio, rank);
  k_newmem<<<(CAPn * Dn / 4) / 256, 256, 0, stream>>>(mem, values, rank, nm);
  k_nmT<<<dim3(CAPn / 64, Dn / 64), 256, 0, stream>>>(nm, nmT);
  k_attnout<<<dim3(8, ROWS / 128), 512, 0, stream>>>(query, nm, nmT, opart, zp2);
  k_merge<<<(ROWS * Dn / 4) / 256, 256, 0, stream>>>(opart, zp2, out);
}